// Round 11
// baseline (483.514 us; speedup 1.0000x reference)
//
#include <hip/hip_runtime.h>

#define B_ 4
#define N_ 16384
#define C_ 128
#define M_ 1024
#define K_ 32
#define NTOT (B_*M_*K_)   /* 131072 */
#define RAD2 0.16f
#define EPS_ 1e-5f

typedef unsigned short ushort_t;
typedef __bf16 bf16x8 __attribute__((ext_vector_type(8)));
typedef float f32x4 __attribute__((ext_vector_type(4)));

__device__ __forceinline__ float b2f(ushort_t u){
  unsigned int x = ((unsigned int)u) << 16;
  return __builtin_bit_cast(float, x);
}
// native RNE convert: compiler emits v_cvt_pk_bf16_f32 for pairs (m240: cast > hand asm)
__device__ __forceinline__ ushort_t f2b(float f){
  return __builtin_bit_cast(ushort_t, (__bf16)f);
}

// ---------------- prep2: transpose + weights + zero (uniform, no ball) ------
// bid [0,2048):    features (B,C,N) f32 -> (B,N,C) bf16 transpose
// bid [2048,2320): weights f32->bf16 (W1 reordered: feat|xyz|0, stride 160)
// bid == 2320:     zero stats (6x256) + pair barrier counters (512)
__global__ __launch_bounds__(256) void prep2_k(
    const float* __restrict__ feat, ushort_t* __restrict__ ftr_t,
    const float* __restrict__ w1, const float* __restrict__ w2, const float* __restrict__ w3,
    ushort_t* __restrict__ W1b, ushort_t* __restrict__ W2b, ushort_t* __restrict__ W3b,
    float* __restrict__ stats, unsigned int* __restrict__ pairbar)
{
  __shared__ float T[32][133];
  int bid = blockIdx.x;
  int t = threadIdx.x;

  if (bid < 2048){
    int b = bid >> 9, ntile = bid & 511;
    int n0 = ntile * 32;
    int nl = t & 31;
    #pragma unroll
    for (int ci = 0; ci < 16; ci++){
      int c = ci*8 + (t >> 5);
      T[nl][c] = feat[((size_t)b*C_ + c)*N_ + n0 + nl];
    }
    __syncthreads();
    #pragma unroll
    for (int ii = 0; ii < 2; ii++){
      int v = ii*256 + t;
      int n2 = v >> 4, seg = v & 15;
      union { ushort_t u[8]; uint4 q; } pk;
      #pragma unroll
      for (int j = 0; j < 8; j++) pk.u[j] = f2b(T[n2][seg*8 + j]);
      *(uint4*)(ftr_t + ((size_t)b*N_ + n0 + n2)*C_ + seg*8) = pk.q;
    }
  } else if (bid < 2320){
    const int T1 = 128*160, T2 = 128*128;
    int e = (bid - 2048)*256 + t;   // 272*256 == 20480+16384+32768 exactly
    if (e < T1){
      int o = e / 160, c = e % 160;
      float v = 0.f;
      if (c < 128) v = w1[o*131 + 3 + c];
      else if (c < 131) v = w1[o*131 + (c - 128)];
      W1b[e] = f2b(v);
    } else if (e < T1+T2){
      int e2 = e - T1;
      W2b[e2] = f2b(w2[e2]);
    } else {
      int e3 = e - T1 - T2;
      W3b[e3] = f2b(w3[e3]);
    }
  } else {
    #pragma unroll
    for (int j = 0; j < 6; j++) stats[j*256 + t] = 0.f;
    #pragma unroll
    for (int j = t; j < 512; j += 256) pairbar[j] = 0u;
  }
}

// ---------------- ball + conv1 fused: pair-local producer/consumer ----------
// Each block: (a) ball query for its own 4 queries (g = bid*4+wv, round-3
// verified ballot-rank body), (b) pair barrier (blocks 2k,2k+1 together own
// queries 8k..8k+7 = conv1 pair's groups; release/acquire + threadfence for
// cross-XCD visibility), (c) conv1 verbatim (col0=(bid&1)*64, blk=bid>>1).
// Tail-pair ball scans overlap other pairs' conv1 on the same CUs.
// Progress: grid 1024 == co-residency capacity at (256,4); pairs are
// adjacent in dispatch order, completed pairs retire -> no deadlock.
__global__ __launch_bounds__(256, 4) void ballconv1_k(
    const float* __restrict__ xyz, const int* __restrict__ indices,
    float* new_xyz, int* idx,
    const ushort_t* __restrict__ ftr_t,
    const ushort_t* __restrict__ W1b, const float* __restrict__ b1,
    ushort_t* __restrict__ Y1, float* __restrict__ sumO, float* __restrict__ sqO,
    unsigned int* pairbar)
{
  __shared__ alignas(16) ushort_t Xs[2][32*168];
  __shared__ alignas(16) float Ys[2][32*68];
  int t = threadIdx.x;
  int bid = blockIdx.x;

  // ---------------- phase a: ball query (round-3 verified body) ------------
  {
    int wv = t >> 6, lane = t & 63;
    int g = bid*4 + wv;
    int b = g >> 10;
    const float* pb = xyz + (size_t)b*N_*3;
    const float4* pb4 = (const float4*)pb;
    int qi = indices[g];
    float qx = pb[qi*3+0], qy = pb[qi*3+1], qz = pb[qi*3+2];
    if (lane < 3) new_xyz[g*3 + lane] = pb[qi*3 + lane];

    int cnt = 0, firstIdx = 0;
    int* op = idx + g*K_;

    float4 buf0[6], buf1[6];
    #pragma unroll
    for (int i = 0; i < 6; i++) buf0[i] = pb4[lane*6 + i];

    unsigned long long below = (lane == 0) ? 0ull : ((~0ull) >> (64 - lane));

    auto process = [&](const float4* buf, int chunk){
      const float* f = (const float*)buf;
      unsigned int local_mask = 0;
      #pragma unroll
      for (int j = 0; j < 8; j++){
        float dx = f[j*3+0]-qx, dy = f[j*3+1]-qy, dz = f[j*3+2]-qz;
        if (dx*dx + dy*dy + dz*dz < RAD2) local_mask |= (1u << j);
      }
      unsigned long long many = __ballot(local_mask != 0);
      if (many == 0ull) return;
      int base = chunk*512;
      unsigned long long mj[8];
      #pragma unroll
      for (int j = 0; j < 8; j++) mj[j] = __ballot((local_mask >> j) & 1u);
      int excl = 0, total = 0;
      #pragma unroll
      for (int j = 0; j < 8; j++){
        excl  += __popcll(mj[j] & below);
        total += __popcll(mj[j]);
      }
      if (cnt == 0){
        int l0 = __builtin_ctzll(many);
        int j0 = 0;
        #pragma unroll
        for (int j = 7; j >= 0; j--) if ((mj[j] >> l0) & 1ull) j0 = j;
        firstIdx = base + l0*8 + j0;
      }
      int sl = cnt + excl;
      unsigned int m = local_mask;
      while (m && sl < K_){
        int j = __builtin_ctz(m); m &= m - 1u;
        op[sl++] = base + lane*8 + j;
      }
      cnt += total;
    };

    for (int chunk = 0; chunk < 32; chunk += 2){
      if (chunk + 1 < 32){
        #pragma unroll
        for (int i = 0; i < 6; i++) buf1[i] = pb4[(chunk+1)*384 + lane*6 + i];
      }
      process(buf0, chunk);
      if (cnt >= K_) break;
      if (chunk + 2 < 32){
        #pragma unroll
        for (int i = 0; i < 6; i++) buf0[i] = pb4[(chunk+2)*384 + lane*6 + i];
      }
      process(buf1, chunk + 1);
      if (cnt >= K_) break;
    }
    if (cnt < K_){
      for (int s = cnt + lane; s < K_; s += 64) op[s] = firstIdx;
    }
  }

  // ---------------- phase b: pair barrier ----------------------------------
  __syncthreads();
  __threadfence();
  if (t == 0){
    __hip_atomic_fetch_add(&pairbar[bid >> 1], 1u, __ATOMIC_RELEASE, __HIP_MEMORY_SCOPE_AGENT);
    while (__hip_atomic_load(&pairbar[bid >> 1], __ATOMIC_ACQUIRE, __HIP_MEMORY_SCOPE_AGENT) < 2u) {}
  }
  __syncthreads();
  __threadfence();

  // ---------------- phase c: conv1 (round-10 verified body) ----------------
  {
    int wv = t >> 6, lane = t & 63, quad = lane >> 4, l15 = lane & 15;
    int row = t >> 3, chunk = t & 7;
    int col0 = (bid & 1) * 64;
    int blk = bid >> 1;

    if (t < 128){
      int rr = t >> 2, cc = t & 3;
      *(uint4*)(Xs[0] + rr*168 + 128 + cc*8) = make_uint4(0,0,0,0);
      *(uint4*)(Xs[1] + rr*168 + 128 + cc*8) = make_uint4(0,0,0,0);
    }
    bf16x8 wf[5];
    #pragma unroll
    for (int kt = 0; kt < 5; kt++)
      wf[kt] = *(const bf16x8*)(W1b + (col0 + wv*16 + l15)*160 + kt*32 + quad*8);
    float bs_r = b1[col0 + wv*16 + l15];
    float s = 0.f, s2 = 0.f;

    const int GPB = 8;
    int g0 = blk * GPB;
    int b = g0 >> 10;
    int ia[GPB], ibv[GPB];
    #pragma unroll
    for (int i = 0; i < GPB; i++){
      ia[i]  = idx[(g0+i)*K_ + row];
      ibv[i] = idx[(g0+i)*K_ + (t & 31)];
    }
    uint4 r0, r1;
    float p3x, p3y, p3z, q3x, q3y, q3z;
    {
      const ushort_t* src = ftr_t + ((size_t)b*N_ + ia[0])*C_ + chunk*16;
      r0 = *(const uint4*)src; r1 = *(const uint4*)(src + 8);
      if (t < 32){
        const float* pp = xyz + ((size_t)b*N_ + ibv[0])*3;
        const float* qq = new_xyz + (size_t)g0*3;
        p3x = pp[0]; p3y = pp[1]; p3z = pp[2];
        q3x = qq[0]; q3y = qq[1]; q3z = qq[2];
      }
    }
    for (int i = 0; i < GPB; i++){
      int p = i & 1;
      ushort_t* X = Xs[p];
      *(uint4*)(X + row*168 + chunk*16) = r0;
      *(uint4*)(X + row*168 + chunk*16 + 8) = r1;
      if (t < 32){
        unsigned int u0 = (unsigned int)f2b(p3x-q3x) | ((unsigned int)f2b(p3y-q3y) << 16);
        unsigned int u1 = (unsigned int)f2b(p3z-q3z);
        *(uint2*)(X + t*168 + 128) = make_uint2(u0, u1);
      }
      if (i + 1 < GPB){
        const ushort_t* src = ftr_t + ((size_t)b*N_ + ia[i+1])*C_ + chunk*16;
        r0 = *(const uint4*)src; r1 = *(const uint4*)(src + 8);
        if (t < 32){
          const float* pp = xyz + ((size_t)b*N_ + ibv[i+1])*3;
          const float* qq = new_xyz + (size_t)(g0+i+1)*3;
          p3x = pp[0]; p3y = pp[1]; p3z = pp[2];
          q3x = qq[0]; q3y = qq[1]; q3z = qq[2];
        }
      }
      __syncthreads();
      bf16x8 af[2][5];
      #pragma unroll
      for (int mt = 0; mt < 2; mt++)
        #pragma unroll
        for (int kt = 0; kt < 5; kt++)
          af[mt][kt] = *(const bf16x8*)(X + (mt*16 + l15)*168 + kt*32 + quad*8);
      f32x4 acc[2] = {(f32x4){0,0,0,0}, (f32x4){0,0,0,0}};
      #pragma unroll
      for (int kt = 0; kt < 5; kt++){
        acc[0] = __builtin_amdgcn_mfma_f32_16x16x32_bf16(af[0][kt], wf[kt], acc[0], 0,0,0);
        acc[1] = __builtin_amdgcn_mfma_f32_16x16x32_bf16(af[1][kt], wf[kt], acc[1], 0,0,0);
      }
      {
        int o = wv*16 + l15;
        float* Yw = Ys[p];
        #pragma unroll
        for (int mt = 0; mt < 2; mt++)
          #pragma unroll
          for (int r = 0; r < 4; r++){
            float v = acc[mt][r] + bs_r;
            s += v; s2 += v*v;
            Yw[(mt*16 + quad*4 + r)*68 + o] = v;
          }
      }
      if (i > 0){
        const float* yp = &Ys[p^1][row*68 + chunk*8];
        f32x4 y0 = *(const f32x4*)(yp);
        f32x4 y1 = *(const f32x4*)(yp + 4);
        union { ushort_t u[8]; uint4 q; } p0;
        #pragma unroll
        for (int j = 0; j < 4; j++){
          p0.u[j] = f2b(y0[j]); p0.u[4+j] = f2b(y1[j]);
        }
        *(uint4*)(Y1 + ((size_t)(g0+i-1)*K_ + row)*128 + col0 + chunk*8) = p0.q;
      }
    }
    __syncthreads();
    {
      const float* yp = &Ys[(GPB-1)&1][row*68 + chunk*8];
      f32x4 y0 = *(const f32x4*)(yp);
      f32x4 y1 = *(const f32x4*)(yp + 4);
      union { ushort_t u[8]; uint4 q; } p0;
      #pragma unroll
      for (int j = 0; j < 4; j++){
        p0.u[j] = f2b(y0[j]); p0.u[4+j] = f2b(y1[j]);
      }
      *(uint4*)(Y1 + ((size_t)(g0+GPB-1)*K_ + row)*128 + col0 + chunk*8) = p0.q;
    }
    s  += __shfl_xor(s, 16);  s  += __shfl_xor(s, 32);
    s2 += __shfl_xor(s2, 16); s2 += __shfl_xor(s2, 32);
    if (quad == 0){
      int o = col0 + wv*16 + l15;
      atomicAdd(&sumO[o], s);
      atomicAdd(&sqO[o], s2);
    }
  }
}

// ---------------- conv2/conv3: column-split pairs, BN staging, W in regs ----
// Round-10 verified: A-fragments loaded inside the kt loop; MINB=4.
template<int COUT, bool MAXMIN, int MINB>
__global__ __launch_bounds__(256, MINB) void convB_k(
    const ushort_t* __restrict__ Yin, const ushort_t* __restrict__ Wb,
    const float* __restrict__ bias, const float* __restrict__ g_bn,
    const float* __restrict__ beta_bn, const float* __restrict__ sumI,
    const float* __restrict__ sqI, ushort_t* __restrict__ Yout,
    unsigned int* __restrict__ Ymm, float* __restrict__ sumO, float* __restrict__ sqO)
{
  constexpr int HALF = COUT/2;
  constexpr int NT = HALF/64;           // col-tiles of 16 per wave
  __shared__ alignas(16) ushort_t Xs[2][32*136];
  __shared__ alignas(16) float Ys[MAXMIN ? 1 : 2][MAXMIN ? 4 : 32*68];
  int t = threadIdx.x;
  int wv = t >> 6, lane = t & 63, quad = lane >> 4, l15 = lane & 15;
  int row = t >> 3, chunk = t & 7;
  int col0 = (blockIdx.x & 1) * HALF;
  int blk = blockIdx.x >> 1;

  float a_r[16], d_r[16];
  #pragma unroll
  for (int j = 0; j < 16; j++){
    int c = chunk*16 + j;
    float mu  = sumI[c] * (1.f/NTOT);
    float var = sqI[c]  * (1.f/NTOT) - mu*mu;
    float a = g_bn[c] * rsqrtf(var + EPS_);
    a_r[j] = a; d_r[j] = beta_bn[c] - a*mu;
  }
  bf16x8 wf[NT][4];
  #pragma unroll
  for (int nt = 0; nt < NT; nt++)
    #pragma unroll
    for (int kt = 0; kt < 4; kt++)
      wf[nt][kt] = *(const bf16x8*)(Wb + (col0 + wv*(NT*16) + nt*16 + l15)*128 + kt*32 + quad*8);
  float bs_r[NT];
  #pragma unroll
  for (int nt = 0; nt < NT; nt++) bs_r[nt] = bias[col0 + wv*(NT*16) + nt*16 + l15];
  float s[NT], s2[NT];
  #pragma unroll
  for (int nt = 0; nt < NT; nt++){ s[nt] = 0.f; s2[nt] = 0.f; }

  const int GPB = 8;
  int g0 = blk * GPB;
  uint4 r0, r1;
  {
    const ushort_t* src = Yin + ((size_t)g0*K_ + row)*128 + chunk*16;
    r0 = *(const uint4*)src; r1 = *(const uint4*)(src + 8);
  }
  for (int i = 0; i < GPB; i++){
    int p = i & 1;
    int g = g0 + i;
    ushort_t* X = Xs[p];
    union { ushort_t u[8]; uint4 q; } i0, i1, o0, o1;
    i0.q = r0; i1.q = r1;
    #pragma unroll
    for (int j = 0; j < 8; j++){
      o0.u[j] = f2b(fmaxf(a_r[j]  *b2f(i0.u[j]) + d_r[j],   0.f));
      o1.u[j] = f2b(fmaxf(a_r[8+j]*b2f(i1.u[j]) + d_r[8+j], 0.f));
    }
    *(uint4*)(X + row*136 + chunk*16) = o0.q;
    *(uint4*)(X + row*136 + chunk*16 + 8) = o1.q;
    if (i + 1 < GPB){
      const ushort_t* src = Yin + ((size_t)(g+1)*K_ + row)*128 + chunk*16;
      r0 = *(const uint4*)src; r1 = *(const uint4*)(src + 8);
    }
    __syncthreads();
    f32x4 acc[NT][2];
    #pragma unroll
    for (int nt = 0; nt < NT; nt++){ acc[nt][0] = (f32x4){0,0,0,0}; acc[nt][1] = (f32x4){0,0,0,0}; }
    #pragma unroll
    for (int kt = 0; kt < 4; kt++){
      bf16x8 A0 = *(const bf16x8*)(X + (l15)*136      + kt*32 + quad*8);
      bf16x8 A1 = *(const bf16x8*)(X + (16 + l15)*136 + kt*32 + quad*8);
      #pragma unroll
      for (int nt = 0; nt < NT; nt++){
        acc[nt][0] = __builtin_amdgcn_mfma_f32_16x16x32_bf16(A0, wf[nt][kt], acc[nt][0], 0,0,0);
        acc[nt][1] = __builtin_amdgcn_mfma_f32_16x16x32_bf16(A1, wf[nt][kt], acc[nt][1], 0,0,0);
      }
    }
    if constexpr (!MAXMIN){
      // NT == 1: wave covers cols col0 + wv*16 + l15
      {
        int o = wv*16 + l15;
        float* Yw = Ys[p];
        #pragma unroll
        for (int mt = 0; mt < 2; mt++)
          #pragma unroll
          for (int r = 0; r < 4; r++){
            float v = acc[0][mt][r] + bs_r[0];
            s[0] += v; s2[0] += v*v;
            Yw[(mt*16 + quad*4 + r)*68 + o] = v;
          }
      }
      if (i > 0){
        const float* yp = &Ys[p^1][row*68 + chunk*8];
        f32x4 y0 = *(const f32x4*)(yp);
        f32x4 y1 = *(const f32x4*)(yp + 4);
        union { ushort_t u[8]; uint4 q; } p0;
        #pragma unroll
        for (int j = 0; j < 4; j++){
          p0.u[j] = f2b(y0[j]); p0.u[4+j] = f2b(y1[j]);
        }
        *(uint4*)(Yout + ((size_t)(g-1)*K_ + row)*128 + col0 + chunk*8) = p0.q;
      }
    } else {
      #pragma unroll
      for (int nt = 0; nt < NT; nt++){
        float v0 = acc[nt][0][0] + bs_r[nt];
        float mx = v0, mn = v0;
        s[nt] += v0; s2[nt] += v0*v0;
        #pragma unroll
        for (int mt = 0; mt < 2; mt++)
          #pragma unroll
          for (int r = 0; r < 4; r++){
            if (mt == 0 && r == 0) continue;
            float v = acc[nt][mt][r] + bs_r[nt];
            s[nt] += v; s2[nt] += v*v;
            mx = fmaxf(mx, v); mn = fminf(mn, v);
          }
        mx = fmaxf(mx, __shfl_xor(mx, 16)); mx = fmaxf(mx, __shfl_xor(mx, 32));
        mn = fminf(mn, __shfl_xor(mn, 16)); mn = fminf(mn, __shfl_xor(mn, 32));
        if (quad == 0){
          int o = col0 + wv*(NT*16) + nt*16 + l15;
          Ymm[(size_t)g*256 + o] = (unsigned int)f2b(mx) | ((unsigned int)f2b(mn) << 16);
        }
      }
      // no trailing barrier: next iteration writes the other Xs buffer
    }
  }
  if constexpr (!MAXMIN){
    __syncthreads();
    const float* yp = &Ys[(GPB-1)&1][row*68 + chunk*8];
    f32x4 y0 = *(const f32x4*)(yp);
    f32x4 y1 = *(const f32x4*)(yp + 4);
    union { ushort_t u[8]; uint4 q; } p0;
    #pragma unroll
    for (int j = 0; j < 4; j++){
      p0.u[j] = f2b(y0[j]); p0.u[4+j] = f2b(y1[j]);
    }
    *(uint4*)(Yout + ((size_t)(g0+GPB-1)*K_ + row)*128 + col0 + chunk*8) = p0.q;
  }
  #pragma unroll
  for (int nt = 0; nt < NT; nt++){
    s[nt]  += __shfl_xor(s[nt], 16);  s[nt]  += __shfl_xor(s[nt], 32);
    s2[nt] += __shfl_xor(s2[nt], 16); s2[nt] += __shfl_xor(s2[nt], 32);
    if (quad == 0){
      int o = col0 + wv*(NT*16) + nt*16 + l15;
      atomicAdd(&sumO[o], s[nt]);
      atomicAdd(&sqO[o], s2[nt]);
    }
  }
}

// ---------------- finalize: BN3 from max/min pairs, transposed store --------
__global__ __launch_bounds__(256) void finalize_k(
    const unsigned int* __restrict__ Ymm, const float* __restrict__ g3,
    const float* __restrict__ beta3, const float* __restrict__ sum3,
    const float* __restrict__ sq3, float* __restrict__ out)
{
  __shared__ float T[16][264];
  __shared__ float abn[256], dbn[256];
  int t = threadIdx.x;
  int b = blockIdx.x >> 6;
  int m0 = (blockIdx.x & 63) * 16;
  {
    float mu  = sum3[t] * (1.f/NTOT);
    float var = sq3[t]  * (1.f/NTOT) - mu*mu;
    float a = g3[t] * rsqrtf(var + EPS_);
    abn[t] = a; dbn[t] = beta3[t] - a*mu;
  }
  __syncthreads();
  #pragma unroll
  for (int i = 0; i < 4; i++){
    int v4 = i*256 + t;
    int m = v4 >> 6, oq = (v4 & 63) * 4;
    uint4 w = *(const uint4*)(Ymm + ((size_t)(b*M_ + m0 + m))*256 + oq);
    unsigned int wsv[4] = {w.x, w.y, w.z, w.w};
    float r[4];
    #pragma unroll
    for (int j = 0; j < 4; j++){
      int o = oq + j;
      float mx = b2f((ushort_t)(wsv[j] & 0xffffu));
      float mn = b2f((ushort_t)(wsv[j] >> 16));
      float a = abn[o];
      float val = (a >= 0.f) ? (a*mx + dbn[o]) : (a*mn + dbn[o]);
      r[j] = fmaxf(val, 0.f);
    }
    *(f32x4*)(&T[m][oq]) = *(f32x4*)r;
  }
  __syncthreads();
  #pragma unroll
  for (int p = 0; p < 4; p++){
    int o = p*64 + (t >> 2), c = t & 3;
    float4 v = make_float4(T[c*4+0][o], T[c*4+1][o], T[c*4+2][o], T[c*4+3][o]);
    *(float4*)(out + ((size_t)(b*256 + o))*M_ + m0 + c*4) = v;
  }
}

extern "C" void kernel_launch(void* const* d_in, const int* in_sizes, int n_in,
                              void* d_out, int out_size, void* d_ws, size_t ws_size,
                              hipStream_t stream)
{
  (void)in_sizes; (void)n_in; (void)out_size; (void)ws_size;
  const float* xyz  = (const float*)d_in[0];
  const float* feat = (const float*)d_in[1];
  const int*   inds = (const int*)d_in[2];
  const float* w1 = (const float*)d_in[3];
  const float* b1 = (const float*)d_in[4];
  const float* g1 = (const float*)d_in[5];
  const float* be1= (const float*)d_in[6];
  const float* w2 = (const float*)d_in[7];
  const float* b2 = (const float*)d_in[8];
  const float* g2 = (const float*)d_in[9];
  const float* be2= (const float*)d_in[10];
  const float* w3 = (const float*)d_in[11];
  const float* b3 = (const float*)d_in[12];
  const float* g3 = (const float*)d_in[13];
  const float* be3= (const float*)d_in[14];

  char* ws = (char*)d_ws;
  float* stats = (float*)ws;
  float* s1sum = stats + 0*256;  float* s1sq = stats + 1*256;
  float* s2sum = stats + 2*256;  float* s2sq = stats + 3*256;
  float* s3sum = stats + 4*256;  float* s3sq = stats + 5*256;
  size_t off = 6*256*sizeof(float);
  unsigned int* pairbar = (unsigned int*)(ws + off); off += 512*sizeof(unsigned int);
  int* idx = (int*)(ws + off);                off += (size_t)B_*M_*K_*4;
  ushort_t* ftr_t = (ushort_t*)(ws + off);    off += (size_t)B_*N_*C_*2;
  ushort_t* W1b = (ushort_t*)(ws + off);      off += 128*160*2;
  ushort_t* W2b = (ushort_t*)(ws + off);      off += 128*128*2;
  ushort_t* W3b = (ushort_t*)(ws + off);      off += 256*128*2;
  ushort_t* Y1 = (ushort_t*)(ws + off);       off += (size_t)NTOT*128*2;
  ushort_t* Y2 = (ushort_t*)(ws + off);       off += (size_t)NTOT*128*2;
  unsigned int* Ymm = (unsigned int*)(ws + off); off += (size_t)B_*M_*256*4;

  float* new_xyz  = (float*)d_out;
  float* out_feat = (float*)d_out + (size_t)B_*M_*3;

  prep2_k<<<2321, 256, 0, stream>>>(feat, ftr_t, w1, w2, w3, W1b, W2b, W3b,
                                    stats, pairbar);
  ballconv1_k<<<1024, 256, 0, stream>>>(xyz, inds, new_xyz, idx, ftr_t,
                                        W1b, b1, Y1, s1sum, s1sq, pairbar);
  convB_k<128,false,4><<<1024, 256, 0, stream>>>(Y1, W2b, b2, g1, be1, s1sum, s1sq, Y2, nullptr, s2sum, s2sq);
  convB_k<256,true ,4><<<1024, 256, 0, stream>>>(Y2, W3b, b3, g2, be2, s2sum, s2sq, nullptr, Ymm, s3sum, s3sq);
  finalize_k<<<256, 256, 0, stream>>>(Ymm, g3, be3, s3sum, s3sq, out_feat);
}

// Round 12
// 215.161 us; speedup vs baseline: 2.2472x; 2.2472x over previous
//
#include <hip/hip_runtime.h>

#define B_ 4
#define N_ 16384
#define C_ 128
#define M_ 1024
#define K_ 32
#define NTOT (B_*M_*K_)   /* 131072 */
#define RAD2 0.16f
#define EPS_ 1e-5f

typedef unsigned short ushort_t;
typedef __bf16 bf16x8 __attribute__((ext_vector_type(8)));
typedef float f32x4 __attribute__((ext_vector_type(4)));

__device__ __forceinline__ float b2f(ushort_t u){
  unsigned int x = ((unsigned int)u) << 16;
  return __builtin_bit_cast(float, x);
}
// native RNE convert: compiler emits v_cvt_pk_bf16_f32 for pairs (m240: cast > hand asm)
__device__ __forceinline__ ushort_t f2b(float f){
  return __builtin_bit_cast(ushort_t, (__bf16)f);
}

// ---------------- prep2: transpose + weights + zero (uniform, no ball) ------
// bid [0,2048):    features (B,C,N) f32 -> (B,N,C) bf16 transpose
// bid [2048,2320): weights f32->bf16 (W1 reordered: feat|xyz|0, stride 160)
// bid == 2320:     zero stats (6x256)
__global__ __launch_bounds__(256) void prep2_k(
    const float* __restrict__ feat, ushort_t* __restrict__ ftr_t,
    const float* __restrict__ w1, const float* __restrict__ w2, const float* __restrict__ w3,
    ushort_t* __restrict__ W1b, ushort_t* __restrict__ W2b, ushort_t* __restrict__ W3b,
    float* __restrict__ stats)
{
  __shared__ float T[32][133];
  int bid = blockIdx.x;
  int t = threadIdx.x;

  if (bid < 2048){
    int b = bid >> 9, ntile = bid & 511;
    int n0 = ntile * 32;
    int nl = t & 31;
    #pragma unroll
    for (int ci = 0; ci < 16; ci++){
      int c = ci*8 + (t >> 5);
      T[nl][c] = feat[((size_t)b*C_ + c)*N_ + n0 + nl];
    }
    __syncthreads();
    #pragma unroll
    for (int ii = 0; ii < 2; ii++){
      int v = ii*256 + t;
      int n2 = v >> 4, seg = v & 15;
      union { ushort_t u[8]; uint4 q; } pk;
      #pragma unroll
      for (int j = 0; j < 8; j++) pk.u[j] = f2b(T[n2][seg*8 + j]);
      *(uint4*)(ftr_t + ((size_t)b*N_ + n0 + n2)*C_ + seg*8) = pk.q;
    }
  } else if (bid < 2320){
    const int T1 = 128*160, T2 = 128*128;
    int e = (bid - 2048)*256 + t;   // 272*256 == 20480+16384+32768 exactly
    if (e < T1){
      int o = e / 160, c = e % 160;
      float v = 0.f;
      if (c < 128) v = w1[o*131 + 3 + c];
      else if (c < 131) v = w1[o*131 + (c - 128)];
      W1b[e] = f2b(v);
    } else if (e < T1+T2){
      int e2 = e - T1;
      W2b[e2] = f2b(w2[e2]);
    } else {
      int e3 = e - T1 - T2;
      W3b[e3] = f2b(w3[e3]);
    }
  } else {
    #pragma unroll
    for (int j = 0; j < 6; j++) stats[j*256 + t] = 0.f;
  }
}

// ---------------- ball + conv1 fused: NO cross-block sync -------------------
// Each block redundantly computes ALL 8 queries of its conv1 pair-group
// (4 waves x 2 interleaved queries over one shared chunk load: loads =
// max(need0,need1) not sum). Results pass through LDS (idx_s/nxyz_s);
// global idx buffer eliminated; only sync is one __syncthreads.
// (Round-11's agent-scope acquire spin caused an L1-invalidate storm,
// HBM 850->174 GB/s — cross-block spin barriers are not viable on CDNA.)
// Fast-ball blocks start conv1 while straggler blocks still scan ->
// the ~40us ball tail leaves the critical path.
// LDS: 21504+17408+1024+96 = 40032B -> 4 blocks/CU (160128 <= 163840).
__global__ __launch_bounds__(256, 4) void ballconv1_k(
    const float* __restrict__ xyz, const int* __restrict__ indices,
    float* __restrict__ new_xyz,
    const ushort_t* __restrict__ ftr_t,
    const ushort_t* __restrict__ W1b, const float* __restrict__ b1,
    ushort_t* __restrict__ Y1, float* __restrict__ sumO, float* __restrict__ sqO)
{
  __shared__ alignas(16) ushort_t Xs[2][32*168];
  __shared__ alignas(16) float Ys[2][32*68];
  __shared__ int idx_s[8][32];
  __shared__ float nxyz_s[8][3];
  int t = threadIdx.x;
  int bid = blockIdx.x;
  int blk = bid >> 1;

  // ---------------- phase a: ball for all 8 own queries --------------------
  {
    int wv = t >> 6, lane = t & 63;
    int g0q = blk*8;
    int q0 = g0q + wv*2, q1 = q0 + 1;
    int b = q0 >> 10;                 // 8 consecutive g, same batch
    const float* pb = xyz + (size_t)b*N_*3;
    const float4* pb4 = (const float4*)pb;
    int qi0 = indices[q0], qi1 = indices[q1];
    float q0x = pb[qi0*3+0], q0y = pb[qi0*3+1], q0z = pb[qi0*3+2];
    float q1x = pb[qi1*3+0], q1y = pb[qi1*3+1], q1z = pb[qi1*3+2];
    if (lane < 3){
      new_xyz[q0*3 + lane] = pb[qi0*3 + lane];
      nxyz_s[wv*2][lane]   = pb[qi0*3 + lane];
      new_xyz[q1*3 + lane] = pb[qi1*3 + lane];
      nxyz_s[wv*2+1][lane] = pb[qi1*3 + lane];
    }

    int cnt0 = 0, first0 = 0, cnt1 = 0, first1 = 0;
    int* op0 = &idx_s[wv*2][0];
    int* op1 = &idx_s[wv*2+1][0];

    unsigned long long below = (lane == 0) ? 0ull : ((~0ull) >> (64 - lane));

    auto process = [&](const float4* buf, int chunk, float qx, float qy, float qz,
                       int& cnt, int& firstIdx, int* op){
      const float* f = (const float*)buf;
      unsigned int local_mask = 0;
      #pragma unroll
      for (int j = 0; j < 8; j++){
        float dx = f[j*3+0]-qx, dy = f[j*3+1]-qy, dz = f[j*3+2]-qz;
        if (dx*dx + dy*dy + dz*dz < RAD2) local_mask |= (1u << j);
      }
      unsigned long long many = __ballot(local_mask != 0);
      if (many == 0ull) return;
      int base = chunk*512;
      unsigned long long mj[8];
      #pragma unroll
      for (int j = 0; j < 8; j++) mj[j] = __ballot((local_mask >> j) & 1u);
      int excl = 0, total = 0;
      #pragma unroll
      for (int j = 0; j < 8; j++){
        excl  += __popcll(mj[j] & below);
        total += __popcll(mj[j]);
      }
      if (cnt == 0){
        int l0 = __builtin_ctzll(many);
        int j0 = 0;
        #pragma unroll
        for (int j = 7; j >= 0; j--) if ((mj[j] >> l0) & 1ull) j0 = j;
        firstIdx = base + l0*8 + j0;
      }
      int sl = cnt + excl;
      unsigned int m = local_mask;
      while (m && sl < K_){
        int j = __builtin_ctz(m); m &= m - 1u;
        op[sl++] = base + lane*8 + j;
      }
      cnt += total;
    };

    float4 buf0[6], buf1[6];
    #pragma unroll
    for (int i = 0; i < 6; i++) buf0[i] = pb4[lane*6 + i];

    for (int chunk = 0; chunk < 32; chunk += 2){
      if (chunk + 1 < 32){
        #pragma unroll
        for (int i = 0; i < 6; i++) buf1[i] = pb4[(chunk+1)*384 + lane*6 + i];
      }
      if (cnt0 < K_) process(buf0, chunk, q0x, q0y, q0z, cnt0, first0, op0);
      if (cnt1 < K_) process(buf0, chunk, q1x, q1y, q1z, cnt1, first1, op1);
      if (cnt0 >= K_ && cnt1 >= K_) break;
      if (chunk + 2 < 32){
        #pragma unroll
        for (int i = 0; i < 6; i++) buf0[i] = pb4[(chunk+2)*384 + lane*6 + i];
      }
      if (cnt0 < K_) process(buf1, chunk + 1, q0x, q0y, q0z, cnt0, first0, op0);
      if (cnt1 < K_) process(buf1, chunk + 1, q1x, q1y, q1z, cnt1, first1, op1);
      if (cnt0 >= K_ && cnt1 >= K_) break;
    }
    if (cnt0 < K_){
      for (int s = cnt0 + lane; s < K_; s += 64) op0[s] = first0;
    }
    if (cnt1 < K_){
      for (int s = cnt1 + lane; s < K_; s += 64) op1[s] = first1;
    }
  }

  __syncthreads();

  // ---------------- phase b: conv1 (round-10 body; idx/new_xyz from LDS) ---
  {
    int wv = t >> 6, lane = t & 63, quad = lane >> 4, l15 = lane & 15;
    int row = t >> 3, chunk = t & 7;
    int col0 = (bid & 1) * 64;

    if (t < 128){
      int rr = t >> 2, cc = t & 3;
      *(uint4*)(Xs[0] + rr*168 + 128 + cc*8) = make_uint4(0,0,0,0);
      *(uint4*)(Xs[1] + rr*168 + 128 + cc*8) = make_uint4(0,0,0,0);
    }
    bf16x8 wf[5];
    #pragma unroll
    for (int kt = 0; kt < 5; kt++)
      wf[kt] = *(const bf16x8*)(W1b + (col0 + wv*16 + l15)*160 + kt*32 + quad*8);
    float bs_r = b1[col0 + wv*16 + l15];
    float s = 0.f, s2 = 0.f;

    const int GPB = 8;
    int g0 = blk * GPB;
    int b = g0 >> 10;
    int ia[GPB], ibv[GPB];
    #pragma unroll
    for (int i = 0; i < GPB; i++){
      ia[i]  = idx_s[i][row];
      ibv[i] = idx_s[i][t & 31];
    }
    uint4 r0, r1;
    float p3x, p3y, p3z, q3x, q3y, q3z;
    {
      const ushort_t* src = ftr_t + ((size_t)b*N_ + ia[0])*C_ + chunk*16;
      r0 = *(const uint4*)src; r1 = *(const uint4*)(src + 8);
      if (t < 32){
        const float* pp = xyz + ((size_t)b*N_ + ibv[0])*3;
        p3x = pp[0]; p3y = pp[1]; p3z = pp[2];
        q3x = nxyz_s[0][0]; q3y = nxyz_s[0][1]; q3z = nxyz_s[0][2];
      }
    }
    for (int i = 0; i < GPB; i++){
      int p = i & 1;
      ushort_t* X = Xs[p];
      *(uint4*)(X + row*168 + chunk*16) = r0;
      *(uint4*)(X + row*168 + chunk*16 + 8) = r1;
      if (t < 32){
        unsigned int u0 = (unsigned int)f2b(p3x-q3x) | ((unsigned int)f2b(p3y-q3y) << 16);
        unsigned int u1 = (unsigned int)f2b(p3z-q3z);
        *(uint2*)(X + t*168 + 128) = make_uint2(u0, u1);
      }
      if (i + 1 < GPB){
        const ushort_t* src = ftr_t + ((size_t)b*N_ + ia[i+1])*C_ + chunk*16;
        r0 = *(const uint4*)src; r1 = *(const uint4*)(src + 8);
        if (t < 32){
          const float* pp = xyz + ((size_t)b*N_ + ibv[i+1])*3;
          p3x = pp[0]; p3y = pp[1]; p3z = pp[2];
          q3x = nxyz_s[i+1][0]; q3y = nxyz_s[i+1][1]; q3z = nxyz_s[i+1][2];
        }
      }
      __syncthreads();
      bf16x8 af[2][5];
      #pragma unroll
      for (int mt = 0; mt < 2; mt++)
        #pragma unroll
        for (int kt = 0; kt < 5; kt++)
          af[mt][kt] = *(const bf16x8*)(X + (mt*16 + l15)*168 + kt*32 + quad*8);
      f32x4 acc[2] = {(f32x4){0,0,0,0}, (f32x4){0,0,0,0}};
      #pragma unroll
      for (int kt = 0; kt < 5; kt++){
        acc[0] = __builtin_amdgcn_mfma_f32_16x16x32_bf16(af[0][kt], wf[kt], acc[0], 0,0,0);
        acc[1] = __builtin_amdgcn_mfma_f32_16x16x32_bf16(af[1][kt], wf[kt], acc[1], 0,0,0);
      }
      {
        int o = wv*16 + l15;
        float* Yw = Ys[p];
        #pragma unroll
        for (int mt = 0; mt < 2; mt++)
          #pragma unroll
          for (int r = 0; r < 4; r++){
            float v = acc[mt][r] + bs_r;
            s += v; s2 += v*v;
            Yw[(mt*16 + quad*4 + r)*68 + o] = v;
          }
      }
      if (i > 0){
        const float* yp = &Ys[p^1][row*68 + chunk*8];
        f32x4 y0 = *(const f32x4*)(yp);
        f32x4 y1 = *(const f32x4*)(yp + 4);
        union { ushort_t u[8]; uint4 q; } p0;
        #pragma unroll
        for (int j = 0; j < 4; j++){
          p0.u[j] = f2b(y0[j]); p0.u[4+j] = f2b(y1[j]);
        }
        *(uint4*)(Y1 + ((size_t)(g0+i-1)*K_ + row)*128 + col0 + chunk*8) = p0.q;
      }
    }
    __syncthreads();
    {
      const float* yp = &Ys[(GPB-1)&1][row*68 + chunk*8];
      f32x4 y0 = *(const f32x4*)(yp);
      f32x4 y1 = *(const f32x4*)(yp + 4);
      union { ushort_t u[8]; uint4 q; } p0;
      #pragma unroll
      for (int j = 0; j < 4; j++){
        p0.u[j] = f2b(y0[j]); p0.u[4+j] = f2b(y1[j]);
      }
      *(uint4*)(Y1 + ((size_t)(g0+GPB-1)*K_ + row)*128 + col0 + chunk*8) = p0.q;
    }
    s  += __shfl_xor(s, 16);  s  += __shfl_xor(s, 32);
    s2 += __shfl_xor(s2, 16); s2 += __shfl_xor(s2, 32);
    if (quad == 0){
      int o = col0 + wv*16 + l15;
      atomicAdd(&sumO[o], s);
      atomicAdd(&sqO[o], s2);
    }
  }
}

// ---------------- conv2/conv3: column-split pairs, BN staging, W in regs ----
// Round-10 verified: A-fragments loaded inside the kt loop; MINB=4.
template<int COUT, bool MAXMIN, int MINB>
__global__ __launch_bounds__(256, MINB) void convB_k(
    const ushort_t* __restrict__ Yin, const ushort_t* __restrict__ Wb,
    const float* __restrict__ bias, const float* __restrict__ g_bn,
    const float* __restrict__ beta_bn, const float* __restrict__ sumI,
    const float* __restrict__ sqI, ushort_t* __restrict__ Yout,
    unsigned int* __restrict__ Ymm, float* __restrict__ sumO, float* __restrict__ sqO)
{
  constexpr int HALF = COUT/2;
  constexpr int NT = HALF/64;           // col-tiles of 16 per wave
  __shared__ alignas(16) ushort_t Xs[2][32*136];
  __shared__ alignas(16) float Ys[MAXMIN ? 1 : 2][MAXMIN ? 4 : 32*68];
  int t = threadIdx.x;
  int wv = t >> 6, lane = t & 63, quad = lane >> 4, l15 = lane & 15;
  int row = t >> 3, chunk = t & 7;
  int col0 = (blockIdx.x & 1) * HALF;
  int blk = blockIdx.x >> 1;

  float a_r[16], d_r[16];
  #pragma unroll
  for (int j = 0; j < 16; j++){
    int c = chunk*16 + j;
    float mu  = sumI[c] * (1.f/NTOT);
    float var = sqI[c]  * (1.f/NTOT) - mu*mu;
    float a = g_bn[c] * rsqrtf(var + EPS_);
    a_r[j] = a; d_r[j] = beta_bn[c] - a*mu;
  }
  bf16x8 wf[NT][4];
  #pragma unroll
  for (int nt = 0; nt < NT; nt++)
    #pragma unroll
    for (int kt = 0; kt < 4; kt++)
      wf[nt][kt] = *(const bf16x8*)(Wb + (col0 + wv*(NT*16) + nt*16 + l15)*128 + kt*32 + quad*8);
  float bs_r[NT];
  #pragma unroll
  for (int nt = 0; nt < NT; nt++) bs_r[nt] = bias[col0 + wv*(NT*16) + nt*16 + l15];
  float s[NT], s2[NT];
  #pragma unroll
  for (int nt = 0; nt < NT; nt++){ s[nt] = 0.f; s2[nt] = 0.f; }

  const int GPB = 8;
  int g0 = blk * GPB;
  uint4 r0, r1;
  {
    const ushort_t* src = Yin + ((size_t)g0*K_ + row)*128 + chunk*16;
    r0 = *(const uint4*)src; r1 = *(const uint4*)(src + 8);
  }
  for (int i = 0; i < GPB; i++){
    int p = i & 1;
    int g = g0 + i;
    ushort_t* X = Xs[p];
    union { ushort_t u[8]; uint4 q; } i0, i1, o0, o1;
    i0.q = r0; i1.q = r1;
    #pragma unroll
    for (int j = 0; j < 8; j++){
      o0.u[j] = f2b(fmaxf(a_r[j]  *b2f(i0.u[j]) + d_r[j],   0.f));
      o1.u[j] = f2b(fmaxf(a_r[8+j]*b2f(i1.u[j]) + d_r[8+j], 0.f));
    }
    *(uint4*)(X + row*136 + chunk*16) = o0.q;
    *(uint4*)(X + row*136 + chunk*16 + 8) = o1.q;
    if (i + 1 < GPB){
      const ushort_t* src = Yin + ((size_t)(g+1)*K_ + row)*128 + chunk*16;
      r0 = *(const uint4*)src; r1 = *(const uint4*)(src + 8);
    }
    __syncthreads();
    f32x4 acc[NT][2];
    #pragma unroll
    for (int nt = 0; nt < NT; nt++){ acc[nt][0] = (f32x4){0,0,0,0}; acc[nt][1] = (f32x4){0,0,0,0}; }
    #pragma unroll
    for (int kt = 0; kt < 4; kt++){
      bf16x8 A0 = *(const bf16x8*)(X + (l15)*136      + kt*32 + quad*8);
      bf16x8 A1 = *(const bf16x8*)(X + (16 + l15)*136 + kt*32 + quad*8);
      #pragma unroll
      for (int nt = 0; nt < NT; nt++){
        acc[nt][0] = __builtin_amdgcn_mfma_f32_16x16x32_bf16(A0, wf[nt][kt], acc[nt][0], 0,0,0);
        acc[nt][1] = __builtin_amdgcn_mfma_f32_16x16x32_bf16(A1, wf[nt][kt], acc[nt][1], 0,0,0);
      }
    }
    if constexpr (!MAXMIN){
      // NT == 1: wave covers cols col0 + wv*16 + l15
      {
        int o = wv*16 + l15;
        float* Yw = Ys[p];
        #pragma unroll
        for (int mt = 0; mt < 2; mt++)
          #pragma unroll
          for (int r = 0; r < 4; r++){
            float v = acc[0][mt][r] + bs_r[0];
            s[0] += v; s2[0] += v*v;
            Yw[(mt*16 + quad*4 + r)*68 + o] = v;
          }
      }
      if (i > 0){
        const float* yp = &Ys[p^1][row*68 + chunk*8];
        f32x4 y0 = *(const f32x4*)(yp);
        f32x4 y1 = *(const f32x4*)(yp + 4);
        union { ushort_t u[8]; uint4 q; } p0;
        #pragma unroll
        for (int j = 0; j < 4; j++){
          p0.u[j] = f2b(y0[j]); p0.u[4+j] = f2b(y1[j]);
        }
        *(uint4*)(Yout + ((size_t)(g-1)*K_ + row)*128 + col0 + chunk*8) = p0.q;
      }
    } else {
      #pragma unroll
      for (int nt = 0; nt < NT; nt++){
        float v0 = acc[nt][0][0] + bs_r[nt];
        float mx = v0, mn = v0;
        s[nt] += v0; s2[nt] += v0*v0;
        #pragma unroll
        for (int mt = 0; mt < 2; mt++)
          #pragma unroll
          for (int r = 0; r < 4; r++){
            if (mt == 0 && r == 0) continue;
            float v = acc[nt][mt][r] + bs_r[nt];
            s[nt] += v; s2[nt] += v*v;
            mx = fmaxf(mx, v); mn = fminf(mn, v);
          }
        mx = fmaxf(mx, __shfl_xor(mx, 16)); mx = fmaxf(mx, __shfl_xor(mx, 32));
        mn = fminf(mn, __shfl_xor(mn, 16)); mn = fminf(mn, __shfl_xor(mn, 32));
        if (quad == 0){
          int o = col0 + wv*(NT*16) + nt*16 + l15;
          Ymm[(size_t)g*256 + o] = (unsigned int)f2b(mx) | ((unsigned int)f2b(mn) << 16);
        }
      }
      // no trailing barrier: next iteration writes the other Xs buffer
    }
  }
  if constexpr (!MAXMIN){
    __syncthreads();
    const float* yp = &Ys[(GPB-1)&1][row*68 + chunk*8];
    f32x4 y0 = *(const f32x4*)(yp);
    f32x4 y1 = *(const f32x4*)(yp + 4);
    union { ushort_t u[8]; uint4 q; } p0;
    #pragma unroll
    for (int j = 0; j < 4; j++){
      p0.u[j] = f2b(y0[j]); p0.u[4+j] = f2b(y1[j]);
    }
    *(uint4*)(Yout + ((size_t)(g0+GPB-1)*K_ + row)*128 + col0 + chunk*8) = p0.q;
  }
  #pragma unroll
  for (int nt = 0; nt < NT; nt++){
    s[nt]  += __shfl_xor(s[nt], 16);  s[nt]  += __shfl_xor(s[nt], 32);
    s2[nt] += __shfl_xor(s2[nt], 16); s2[nt] += __shfl_xor(s2[nt], 32);
    if (quad == 0){
      int o = col0 + wv*(NT*16) + nt*16 + l15;
      atomicAdd(&sumO[o], s[nt]);
      atomicAdd(&sqO[o], s2[nt]);
    }
  }
}

// ---------------- finalize: BN3 from max/min pairs, transposed store --------
__global__ __launch_bounds__(256) void finalize_k(
    const unsigned int* __restrict__ Ymm, const float* __restrict__ g3,
    const float* __restrict__ beta3, const float* __restrict__ sum3,
    const float* __restrict__ sq3, float* __restrict__ out)
{
  __shared__ float T[16][264];
  __shared__ float abn[256], dbn[256];
  int t = threadIdx.x;
  int b = blockIdx.x >> 6;
  int m0 = (blockIdx.x & 63) * 16;
  {
    float mu  = sum3[t] * (1.f/NTOT);
    float var = sq3[t]  * (1.f/NTOT) - mu*mu;
    float a = g3[t] * rsqrtf(var + EPS_);
    abn[t] = a; dbn[t] = beta3[t] - a*mu;
  }
  __syncthreads();
  #pragma unroll
  for (int i = 0; i < 4; i++){
    int v4 = i*256 + t;
    int m = v4 >> 6, oq = (v4 & 63) * 4;
    uint4 w = *(const uint4*)(Ymm + ((size_t)(b*M_ + m0 + m))*256 + oq);
    unsigned int wsv[4] = {w.x, w.y, w.z, w.w};
    float r[4];
    #pragma unroll
    for (int j = 0; j < 4; j++){
      int o = oq + j;
      float mx = b2f((ushort_t)(wsv[j] & 0xffffu));
      float mn = b2f((ushort_t)(wsv[j] >> 16));
      float a = abn[o];
      float val = (a >= 0.f) ? (a*mx + dbn[o]) : (a*mn + dbn[o]);
      r[j] = fmaxf(val, 0.f);
    }
    *(f32x4*)(&T[m][oq]) = *(f32x4*)r;
  }
  __syncthreads();
  #pragma unroll
  for (int p = 0; p < 4; p++){
    int o = p*64 + (t >> 2), c = t & 3;
    float4 v = make_float4(T[c*4+0][o], T[c*4+1][o], T[c*4+2][o], T[c*4+3][o]);
    *(float4*)(out + ((size_t)(b*256 + o))*M_ + m0 + c*4) = v;
  }
}

extern "C" void kernel_launch(void* const* d_in, const int* in_sizes, int n_in,
                              void* d_out, int out_size, void* d_ws, size_t ws_size,
                              hipStream_t stream)
{
  (void)in_sizes; (void)n_in; (void)out_size; (void)ws_size;
  const float* xyz  = (const float*)d_in[0];
  const float* feat = (const float*)d_in[1];
  const int*   inds = (const int*)d_in[2];
  const float* w1 = (const float*)d_in[3];
  const float* b1 = (const float*)d_in[4];
  const float* g1 = (const float*)d_in[5];
  const float* be1= (const float*)d_in[6];
  const float* w2 = (const float*)d_in[7];
  const float* b2 = (const float*)d_in[8];
  const float* g2 = (const float*)d_in[9];
  const float* be2= (const float*)d_in[10];
  const float* w3 = (const float*)d_in[11];
  const float* b3 = (const float*)d_in[12];
  const float* g3 = (const float*)d_in[13];
  const float* be3= (const float*)d_in[14];

  char* ws = (char*)d_ws;
  float* stats = (float*)ws;
  float* s1sum = stats + 0*256;  float* s1sq = stats + 1*256;
  float* s2sum = stats + 2*256;  float* s2sq = stats + 3*256;
  float* s3sum = stats + 4*256;  float* s3sq = stats + 5*256;
  size_t off = 6*256*sizeof(float);
  ushort_t* ftr_t = (ushort_t*)(ws + off);    off += (size_t)B_*N_*C_*2;
  ushort_t* W1b = (ushort_t*)(ws + off);      off += 128*160*2;
  ushort_t* W2b = (ushort_t*)(ws + off);      off += 128*128*2;
  ushort_t* W3b = (ushort_t*)(ws + off);      off += 256*128*2;
  ushort_t* Y1 = (ushort_t*)(ws + off);       off += (size_t)NTOT*128*2;
  ushort_t* Y2 = (ushort_t*)(ws + off);       off += (size_t)NTOT*128*2;
  unsigned int* Ymm = (unsigned int*)(ws + off); off += (size_t)B_*M_*256*4;

  float* new_xyz  = (float*)d_out;
  float* out_feat = (float*)d_out + (size_t)B_*M_*3;

  prep2_k<<<2321, 256, 0, stream>>>(feat, ftr_t, w1, w2, w3, W1b, W2b, W3b, stats);
  ballconv1_k<<<1024, 256, 0, stream>>>(xyz, inds, new_xyz, ftr_t,
                                        W1b, b1, Y1, s1sum, s1sq);
  convB_k<128,false,4><<<1024, 256, 0, stream>>>(Y1, W2b, b2, g1, be1, s1sum, s1sq, Y2, nullptr, s2sum, s2sq);
  convB_k<256,true ,4><<<1024, 256, 0, stream>>>(Y2, W3b, b3, g2, be2, s2sum, s2sq, nullptr, Ymm, s3sum, s3sq);
  finalize_k<<<256, 256, 0, stream>>>(Ymm, g3, be3, s3sum, s3sq, out_feat);
}

// Round 13
// 207.304 us; speedup vs baseline: 2.3324x; 1.0379x over previous
//
#include <hip/hip_runtime.h>

#define B_ 4
#define N_ 16384
#define C_ 128
#define M_ 1024
#define K_ 32
#define NTOT (B_*M_*K_)   /* 131072 */
#define RAD2 0.16f
#define EPS_ 1e-5f

typedef unsigned short ushort_t;
typedef __bf16 bf16x8 __attribute__((ext_vector_type(8)));
typedef float f32x4 __attribute__((ext_vector_type(4)));

__device__ __forceinline__ float b2f(ushort_t u){
  unsigned int x = ((unsigned int)u) << 16;
  return __builtin_bit_cast(float, x);
}
// native RNE convert: compiler emits v_cvt_pk_bf16_f32 for pairs (m240: cast > hand asm)
__device__ __forceinline__ ushort_t f2b(float f){
  return __builtin_bit_cast(ushort_t, (__bf16)f);
}

// ---------------- fused prep ------------------------------------------------
// bid [0,1024):    ball query — 1 wave per query (4/block), ballot-ranked
// bid [1024,3072): features (B,C,N) f32 -> (B,N,C) bf16 transpose
// bid [3072,3344): weights f32->bf16 (+stats zero at bid 3072)
// (final: rounds 4-12 prep/fusion experiments all regressed — the ball tail
//  is a data-dependent serial scan, latency-bound; ~40us is its floor here)
__global__ __launch_bounds__(256) void prep_all_k(
    const float* __restrict__ feat, ushort_t* __restrict__ ftr_t,
    const float* __restrict__ xyz, const int* __restrict__ indices,
    float* __restrict__ new_xyz, int* __restrict__ idx,
    const float* __restrict__ w1, const float* __restrict__ w2, const float* __restrict__ w3,
    ushort_t* __restrict__ W1b, ushort_t* __restrict__ W2b, ushort_t* __restrict__ W3b,
    float* __restrict__ stats)
{
  __shared__ float T[32][133];
  int bid = blockIdx.x;
  int t = threadIdx.x;

  if (bid < 1024){
    // ---- ball query: 1 wave per query; rank via ballots (no shfl chains) ----
    int wv = t >> 6, lane = t & 63;
    int g = bid*4 + wv;
    int b = g >> 10;
    const float* pb = xyz + (size_t)b*N_*3;
    const float4* pb4 = (const float4*)pb;
    int qi = indices[g];
    float qx = pb[qi*3+0], qy = pb[qi*3+1], qz = pb[qi*3+2];
    if (lane < 3) new_xyz[g*3 + lane] = pb[qi*3 + lane];

    int cnt = 0, firstIdx = 0;
    int* op = idx + g*K_;

    float4 buf0[6], buf1[6];
    #pragma unroll
    for (int i = 0; i < 6; i++) buf0[i] = pb4[lane*6 + i];

    unsigned long long below = (lane == 0) ? 0ull : ((~0ull) >> (64 - lane));

    auto process = [&](const float4* buf, int chunk){
      const float* f = (const float*)buf;
      unsigned int local_mask = 0;
      #pragma unroll
      for (int j = 0; j < 8; j++){
        float dx = f[j*3+0]-qx, dy = f[j*3+1]-qy, dz = f[j*3+2]-qz;
        if (dx*dx + dy*dy + dz*dz < RAD2) local_mask |= (1u << j);
      }
      unsigned long long many = __ballot(local_mask != 0);
      if (many == 0ull) return;
      int base = chunk*512;
      unsigned long long mj[8];
      #pragma unroll
      for (int j = 0; j < 8; j++) mj[j] = __ballot((local_mask >> j) & 1u);
      int excl = 0, total = 0;
      #pragma unroll
      for (int j = 0; j < 8; j++){
        excl  += __popcll(mj[j] & below);
        total += __popcll(mj[j]);
      }
      if (cnt == 0){
        int l0 = __builtin_ctzll(many);
        int j0 = 0;
        #pragma unroll
        for (int j = 7; j >= 0; j--) if ((mj[j] >> l0) & 1ull) j0 = j;
        firstIdx = base + l0*8 + j0;
      }
      int sl = cnt + excl;
      unsigned int m = local_mask;
      while (m && sl < K_){
        int j = __builtin_ctz(m); m &= m - 1u;
        op[sl++] = base + lane*8 + j;
      }
      cnt += total;
    };

    for (int chunk = 0; chunk < 32; chunk += 2){
      if (chunk + 1 < 32){
        #pragma unroll
        for (int i = 0; i < 6; i++) buf1[i] = pb4[(chunk+1)*384 + lane*6 + i];
      }
      process(buf0, chunk);
      if (cnt >= K_) break;
      if (chunk + 2 < 32){
        #pragma unroll
        for (int i = 0; i < 6; i++) buf0[i] = pb4[(chunk+2)*384 + lane*6 + i];
      }
      process(buf1, chunk + 1);
      if (cnt >= K_) break;
    }
    if (cnt < K_){
      for (int s = cnt + lane; s < K_; s += 64) op[s] = firstIdx;
    }
  } else if (bid < 3072){
    // ---- features (B,C,N) f32 -> (B,N,C) bf16 ----
    int bb = bid - 1024;
    int b = bb >> 9, ntile = bb & 511;
    int n0 = ntile * 32;
    int nl = t & 31;
    #pragma unroll
    for (int ci = 0; ci < 16; ci++){
      int c = ci*8 + (t >> 5);
      T[nl][c] = feat[((size_t)b*C_ + c)*N_ + n0 + nl];
    }
    __syncthreads();
    #pragma unroll
    for (int ii = 0; ii < 2; ii++){
      int v = ii*256 + t;
      int n2 = v >> 4, seg = v & 15;
      union { ushort_t u[8]; uint4 q; } pk;
      #pragma unroll
      for (int j = 0; j < 8; j++) pk.u[j] = f2b(T[n2][seg*8 + j]);
      *(uint4*)(ftr_t + ((size_t)b*N_ + n0 + n2)*C_ + seg*8) = pk.q;
    }
  } else {
    // ---- weights f32 -> bf16 (W1 reordered: feat|xyz|0, stride 160) + stats zero ----
    const int T1 = 128*160, T2 = 128*128;
    int e = (bid - 3072)*256 + t;   // 272*256 == 20480+16384+32768 exactly
    if (e < T1){
      int o = e / 160, c = e % 160;
      float v = 0.f;
      if (c < 128) v = w1[o*131 + 3 + c];
      else if (c < 131) v = w1[o*131 + (c - 128)];
      W1b[e] = f2b(v);
    } else if (e < T1+T2){
      int e2 = e - T1;
      W2b[e2] = f2b(w2[e2]);
    } else {
      int e3 = e - T1 - T2;
      W3b[e3] = f2b(w3[e3]);
    }
    if (bid == 3072){
      #pragma unroll
      for (int j = 0; j < 6; j++) stats[j*256 + t] = 0.f;
    }
  }
}

// ---------------- conv1: column-split pairs (64 cols/block), GPB=8 ----------
// Single barrier per group: Xs AND Ys double-buffered; Ys->global store
// deferred one iteration so barrier(i+1) doubles as the Ys-ready fence.
__global__ __launch_bounds__(256, 4) void conv1_k(
    const float* __restrict__ xyz, const ushort_t* __restrict__ ftr_t,
    const int* __restrict__ idx, const float* __restrict__ new_xyz,
    const ushort_t* __restrict__ W1b, const float* __restrict__ b1,
    ushort_t* __restrict__ Y1, float* __restrict__ sumO, float* __restrict__ sqO)
{
  __shared__ alignas(16) ushort_t Xs[2][32*168];
  __shared__ alignas(16) float Ys[2][32*68];
  int t = threadIdx.x;
  int wv = t >> 6, lane = t & 63, quad = lane >> 4, l15 = lane & 15;
  int row = t >> 3, chunk = t & 7;
  int col0 = (blockIdx.x & 1) * 64;
  int blk = blockIdx.x >> 1;

  if (t < 128){
    int rr = t >> 2, cc = t & 3;
    *(uint4*)(Xs[0] + rr*168 + 128 + cc*8) = make_uint4(0,0,0,0);
    *(uint4*)(Xs[1] + rr*168 + 128 + cc*8) = make_uint4(0,0,0,0);
  }
  bf16x8 wf[5];
  #pragma unroll
  for (int kt = 0; kt < 5; kt++)
    wf[kt] = *(const bf16x8*)(W1b + (col0 + wv*16 + l15)*160 + kt*32 + quad*8);
  float bs_r = b1[col0 + wv*16 + l15];
  float s = 0.f, s2 = 0.f;

  const int GPB = 8;
  int g0 = blk * GPB;
  int b = g0 >> 10;
  int ia[GPB], ibv[GPB];
  #pragma unroll
  for (int i = 0; i < GPB; i++){
    ia[i]  = idx[(g0+i)*K_ + row];
    ibv[i] = idx[(g0+i)*K_ + (t & 31)];
  }
  uint4 r0, r1;
  float p3x, p3y, p3z, q3x, q3y, q3z;
  {
    const ushort_t* src = ftr_t + ((size_t)b*N_ + ia[0])*C_ + chunk*16;
    r0 = *(const uint4*)src; r1 = *(const uint4*)(src + 8);
    if (t < 32){
      const float* pp = xyz + ((size_t)b*N_ + ibv[0])*3;
      const float* qq = new_xyz + (size_t)g0*3;
      p3x = pp[0]; p3y = pp[1]; p3z = pp[2];
      q3x = qq[0]; q3y = qq[1]; q3z = qq[2];
    }
  }
  for (int i = 0; i < GPB; i++){
    int p = i & 1;
    ushort_t* X = Xs[p];
    *(uint4*)(X + row*168 + chunk*16) = r0;
    *(uint4*)(X + row*168 + chunk*16 + 8) = r1;
    if (t < 32){
      unsigned int u0 = (unsigned int)f2b(p3x-q3x) | ((unsigned int)f2b(p3y-q3y) << 16);
      unsigned int u1 = (unsigned int)f2b(p3z-q3z);
      *(uint2*)(X + t*168 + 128) = make_uint2(u0, u1);
    }
    if (i + 1 < GPB){
      const ushort_t* src = ftr_t + ((size_t)b*N_ + ia[i+1])*C_ + chunk*16;
      r0 = *(const uint4*)src; r1 = *(const uint4*)(src + 8);
      if (t < 32){
        const float* pp = xyz + ((size_t)b*N_ + ibv[i+1])*3;
        const float* qq = new_xyz + (size_t)(g0+i+1)*3;
        p3x = pp[0]; p3y = pp[1]; p3z = pp[2];
        q3x = qq[0]; q3y = qq[1]; q3z = qq[2];
      }
    }
    __syncthreads();
    bf16x8 af[2][5];
    #pragma unroll
    for (int mt = 0; mt < 2; mt++)
      #pragma unroll
      for (int kt = 0; kt < 5; kt++)
        af[mt][kt] = *(const bf16x8*)(X + (mt*16 + l15)*168 + kt*32 + quad*8);
    f32x4 acc[2] = {(f32x4){0,0,0,0}, (f32x4){0,0,0,0}};
    #pragma unroll
    for (int kt = 0; kt < 5; kt++){
      acc[0] = __builtin_amdgcn_mfma_f32_16x16x32_bf16(af[0][kt], wf[kt], acc[0], 0,0,0);
      acc[1] = __builtin_amdgcn_mfma_f32_16x16x32_bf16(af[1][kt], wf[kt], acc[1], 0,0,0);
    }
    {
      int o = wv*16 + l15;
      float* Yw = Ys[p];
      #pragma unroll
      for (int mt = 0; mt < 2; mt++)
        #pragma unroll
        for (int r = 0; r < 4; r++){
          float v = acc[mt][r] + bs_r;
          s += v; s2 += v*v;
          Yw[(mt*16 + quad*4 + r)*68 + o] = v;
        }
    }
    if (i > 0){
      const float* yp = &Ys[p^1][row*68 + chunk*8];
      f32x4 y0 = *(const f32x4*)(yp);
      f32x4 y1 = *(const f32x4*)(yp + 4);
      union { ushort_t u[8]; uint4 q; } p0;
      #pragma unroll
      for (int j = 0; j < 4; j++){
        p0.u[j] = f2b(y0[j]); p0.u[4+j] = f2b(y1[j]);
      }
      *(uint4*)(Y1 + ((size_t)(g0+i-1)*K_ + row)*128 + col0 + chunk*8) = p0.q;
    }
  }
  __syncthreads();
  {
    const float* yp = &Ys[(GPB-1)&1][row*68 + chunk*8];
    f32x4 y0 = *(const f32x4*)(yp);
    f32x4 y1 = *(const f32x4*)(yp + 4);
    union { ushort_t u[8]; uint4 q; } p0;
    #pragma unroll
    for (int j = 0; j < 4; j++){
      p0.u[j] = f2b(y0[j]); p0.u[4+j] = f2b(y1[j]);
    }
    *(uint4*)(Y1 + ((size_t)(g0+GPB-1)*K_ + row)*128 + col0 + chunk*8) = p0.q;
  }
  s  += __shfl_xor(s, 16);  s  += __shfl_xor(s, 32);
  s2 += __shfl_xor(s2, 16); s2 += __shfl_xor(s2, 32);
  if (quad == 0){
    int o = col0 + wv*16 + l15;
    atomicAdd(&sumO[o], s);
    atomicAdd(&sqO[o], s2);
  }
}

// ---------------- conv2/conv3: column-split pairs, BN staging, W in regs ----
// Both paths single-barrier per group: Xs dbuf; conv2 additionally dbufs Ys
// with deferred store; conv3 keeps in-register max/min epilogue.
// A-fragments loaded inside the kt loop (live af 32->8 VGPR) -> both fit
// the 128-VGPR cap of MINB=4 -> 4 blocks/CU.
template<int COUT, bool MAXMIN, int MINB>
__global__ __launch_bounds__(256, MINB) void convB_k(
    const ushort_t* __restrict__ Yin, const ushort_t* __restrict__ Wb,
    const float* __restrict__ bias, const float* __restrict__ g_bn,
    const float* __restrict__ beta_bn, const float* __restrict__ sumI,
    const float* __restrict__ sqI, ushort_t* __restrict__ Yout,
    unsigned int* __restrict__ Ymm, float* __restrict__ sumO, float* __restrict__ sqO)
{
  constexpr int HALF = COUT/2;
  constexpr int NT = HALF/64;           // col-tiles of 16 per wave
  __shared__ alignas(16) ushort_t Xs[2][32*136];
  __shared__ alignas(16) float Ys[MAXMIN ? 1 : 2][MAXMIN ? 4 : 32*68];
  int t = threadIdx.x;
  int wv = t >> 6, lane = t & 63, quad = lane >> 4, l15 = lane & 15;
  int row = t >> 3, chunk = t & 7;
  int col0 = (blockIdx.x & 1) * HALF;
  int blk = blockIdx.x >> 1;

  float a_r[16], d_r[16];
  #pragma unroll
  for (int j = 0; j < 16; j++){
    int c = chunk*16 + j;
    float mu  = sumI[c] * (1.f/NTOT);
    float var = sqI[c]  * (1.f/NTOT) - mu*mu;
    float a = g_bn[c] * rsqrtf(var + EPS_);
    a_r[j] = a; d_r[j] = beta_bn[c] - a*mu;
  }
  bf16x8 wf[NT][4];
  #pragma unroll
  for (int nt = 0; nt < NT; nt++)
    #pragma unroll
    for (int kt = 0; kt < 4; kt++)
      wf[nt][kt] = *(const bf16x8*)(Wb + (col0 + wv*(NT*16) + nt*16 + l15)*128 + kt*32 + quad*8);
  float bs_r[NT];
  #pragma unroll
  for (int nt = 0; nt < NT; nt++) bs_r[nt] = bias[col0 + wv*(NT*16) + nt*16 + l15];
  float s[NT], s2[NT];
  #pragma unroll
  for (int nt = 0; nt < NT; nt++){ s[nt] = 0.f; s2[nt] = 0.f; }

  const int GPB = 8;
  int g0 = blk * GPB;
  uint4 r0, r1;
  {
    const ushort_t* src = Yin + ((size_t)g0*K_ + row)*128 + chunk*16;
    r0 = *(const uint4*)src; r1 = *(const uint4*)(src + 8);
  }
  for (int i = 0; i < GPB; i++){
    int p = i & 1;
    int g = g0 + i;
    ushort_t* X = Xs[p];
    union { ushort_t u[8]; uint4 q; } i0, i1, o0, o1;
    i0.q = r0; i1.q = r1;
    #pragma unroll
    for (int j = 0; j < 8; j++){
      o0.u[j] = f2b(fmaxf(a_r[j]  *b2f(i0.u[j]) + d_r[j],   0.f));
      o1.u[j] = f2b(fmaxf(a_r[8+j]*b2f(i1.u[j]) + d_r[8+j], 0.f));
    }
    *(uint4*)(X + row*136 + chunk*16) = o0.q;
    *(uint4*)(X + row*136 + chunk*16 + 8) = o1.q;
    if (i + 1 < GPB){
      const ushort_t* src = Yin + ((size_t)(g+1)*K_ + row)*128 + chunk*16;
      r0 = *(const uint4*)src; r1 = *(const uint4*)(src + 8);
    }
    __syncthreads();
    f32x4 acc[NT][2];
    #pragma unroll
    for (int nt = 0; nt < NT; nt++){ acc[nt][0] = (f32x4){0,0,0,0}; acc[nt][1] = (f32x4){0,0,0,0}; }
    #pragma unroll
    for (int kt = 0; kt < 4; kt++){
      bf16x8 A0 = *(const bf16x8*)(X + (l15)*136      + kt*32 + quad*8);
      bf16x8 A1 = *(const bf16x8*)(X + (16 + l15)*136 + kt*32 + quad*8);
      #pragma unroll
      for (int nt = 0; nt < NT; nt++){
        acc[nt][0] = __builtin_amdgcn_mfma_f32_16x16x32_bf16(A0, wf[nt][kt], acc[nt][0], 0,0,0);
        acc[nt][1] = __builtin_amdgcn_mfma_f32_16x16x32_bf16(A1, wf[nt][kt], acc[nt][1], 0,0,0);
      }
    }
    if constexpr (!MAXMIN){
      // NT == 1: wave covers cols col0 + wv*16 + l15
      {
        int o = wv*16 + l15;
        float* Yw = Ys[p];
        #pragma unroll
        for (int mt = 0; mt < 2; mt++)
          #pragma unroll
          for (int r = 0; r < 4; r++){
            float v = acc[0][mt][r] + bs_r[0];
            s[0] += v; s2[0] += v*v;
            Yw[(mt*16 + quad*4 + r)*68 + o] = v;
          }
      }
      if (i > 0){
        const float* yp = &Ys[p^1][row*68 + chunk*8];
        f32x4 y0 = *(const f32x4*)(yp);
        f32x4 y1 = *(const f32x4*)(yp + 4);
        union { ushort_t u[8]; uint4 q; } p0;
        #pragma unroll
        for (int j = 0; j < 4; j++){
          p0.u[j] = f2b(y0[j]); p0.u[4+j] = f2b(y1[j]);
        }
        *(uint4*)(Yout + ((size_t)(g-1)*K_ + row)*128 + col0 + chunk*8) = p0.q;
      }
    } else {
      #pragma unroll
      for (int nt = 0; nt < NT; nt++){
        float v0 = acc[nt][0][0] + bs_r[nt];
        float mx = v0, mn = v0;
        s[nt] += v0; s2[nt] += v0*v0;
        #pragma unroll
        for (int mt = 0; mt < 2; mt++)
          #pragma unroll
          for (int r = 0; r < 4; r++){
            if (mt == 0 && r == 0) continue;
            float v = acc[nt][mt][r] + bs_r[nt];
            s[nt] += v; s2[nt] += v*v;
            mx = fmaxf(mx, v); mn = fminf(mn, v);
          }
        mx = fmaxf(mx, __shfl_xor(mx, 16)); mx = fmaxf(mx, __shfl_xor(mx, 32));
        mn = fminf(mn, __shfl_xor(mn, 16)); mn = fminf(mn, __shfl_xor(mn, 32));
        if (quad == 0){
          int o = col0 + wv*(NT*16) + nt*16 + l15;
          Ymm[(size_t)g*256 + o] = (unsigned int)f2b(mx) | ((unsigned int)f2b(mn) << 16);
        }
      }
      // no trailing barrier: next iteration writes the other Xs buffer
    }
  }
  if constexpr (!MAXMIN){
    __syncthreads();
    const float* yp = &Ys[(GPB-1)&1][row*68 + chunk*8];
    f32x4 y0 = *(const f32x4*)(yp);
    f32x4 y1 = *(const f32x4*)(yp + 4);
    union { ushort_t u[8]; uint4 q; } p0;
    #pragma unroll
    for (int j = 0; j < 4; j++){
      p0.u[j] = f2b(y0[j]); p0.u[4+j] = f2b(y1[j]);
    }
    *(uint4*)(Yout + ((size_t)(g0+GPB-1)*K_ + row)*128 + col0 + chunk*8) = p0.q;
  }
  #pragma unroll
  for (int nt = 0; nt < NT; nt++){
    s[nt]  += __shfl_xor(s[nt], 16);  s[nt]  += __shfl_xor(s[nt], 32);
    s2[nt] += __shfl_xor(s2[nt], 16); s2[nt] += __shfl_xor(s2[nt], 32);
    if (quad == 0){
      int o = col0 + wv*(NT*16) + nt*16 + l15;
      atomicAdd(&sumO[o], s[nt]);
      atomicAdd(&sqO[o], s2[nt]);
    }
  }
}

// ---------------- finalize: BN3 from max/min pairs, transposed store --------
__global__ __launch_bounds__(256) void finalize_k(
    const unsigned int* __restrict__ Ymm, const float* __restrict__ g3,
    const float* __restrict__ beta3, const float* __restrict__ sum3,
    const float* __restrict__ sq3, float* __restrict__ out)
{
  __shared__ float T[16][264];
  __shared__ float abn[256], dbn[256];
  int t = threadIdx.x;
  int b = blockIdx.x >> 6;
  int m0 = (blockIdx.x & 63) * 16;
  {
    float mu  = sum3[t] * (1.f/NTOT);
    float var = sq3[t]  * (1.f/NTOT) - mu*mu;
    float a = g3[t] * rsqrtf(var + EPS_);
    abn[t] = a; dbn[t] = beta3[t] - a*mu;
  }
  __syncthreads();
  #pragma unroll
  for (int i = 0; i < 4; i++){
    int v4 = i*256 + t;
    int m = v4 >> 6, oq = (v4 & 63) * 4;
    uint4 w = *(const uint4*)(Ymm + ((size_t)(b*M_ + m0 + m))*256 + oq);
    unsigned int wsv[4] = {w.x, w.y, w.z, w.w};
    float r[4];
    #pragma unroll
    for (int j = 0; j < 4; j++){
      int o = oq + j;
      float mx = b2f((ushort_t)(wsv[j] & 0xffffu));
      float mn = b2f((ushort_t)(wsv[j] >> 16));
      float a = abn[o];
      float val = (a >= 0.f) ? (a*mx + dbn[o]) : (a*mn + dbn[o]);
      r[j] = fmaxf(val, 0.f);
    }
    *(f32x4*)(&T[m][oq]) = *(f32x4*)r;
  }
  __syncthreads();
  #pragma unroll
  for (int p = 0; p < 4; p++){
    int o = p*64 + (t >> 2), c = t & 3;
    float4 v = make_float4(T[c*4+0][o], T[c*4+1][o], T[c*4+2][o], T[c*4+3][o]);
    *(float4*)(out + ((size_t)(b*256 + o))*M_ + m0 + c*4) = v;
  }
}

extern "C" void kernel_launch(void* const* d_in, const int* in_sizes, int n_in,
                              void* d_out, int out_size, void* d_ws, size_t ws_size,
                              hipStream_t stream)
{
  (void)in_sizes; (void)n_in; (void)out_size; (void)ws_size;
  const float* xyz  = (const float*)d_in[0];
  const float* feat = (const float*)d_in[1];
  const int*   inds = (const int*)d_in[2];
  const float* w1 = (const float*)d_in[3];
  const float* b1 = (const float*)d_in[4];
  const float* g1 = (const float*)d_in[5];
  const float* be1= (const float*)d_in[6];
  const float* w2 = (const float*)d_in[7];
  const float* b2 = (const float*)d_in[8];
  const float* g2 = (const float*)d_in[9];
  const float* be2= (const float*)d_in[10];
  const float* w3 = (const float*)d_in[11];
  const float* b3 = (const float*)d_in[12];
  const float* g3 = (const float*)d_in[13];
  const float* be3= (const float*)d_in[14];

  char* ws = (char*)d_ws;
  float* stats = (float*)ws;
  float* s1sum = stats + 0*256;  float* s1sq = stats + 1*256;
  float* s2sum = stats + 2*256;  float* s2sq = stats + 3*256;
  float* s3sum = stats + 4*256;  float* s3sq = stats + 5*256;
  size_t off = 6*256*sizeof(float);
  int* idx = (int*)(ws + off);                off += (size_t)B_*M_*K_*4;
  ushort_t* ftr_t = (ushort_t*)(ws + off);    off += (size_t)B_*N_*C_*2;
  ushort_t* W1b = (ushort_t*)(ws + off);      off += 128*160*2;
  ushort_t* W2b = (ushort_t*)(ws + off);      off += 128*128*2;
  ushort_t* W3b = (ushort_t*)(ws + off);      off += 256*128*2;
  ushort_t* Y1 = (ushort_t*)(ws + off);       off += (size_t)NTOT*128*2;
  ushort_t* Y2 = (ushort_t*)(ws + off);       off += (size_t)NTOT*128*2;
  unsigned int* Ymm = (unsigned int*)(ws + off); off += (size_t)B_*M_*256*4;

  float* new_xyz  = (float*)d_out;
  float* out_feat = (float*)d_out + (size_t)B_*M_*3;

  prep_all_k<<<3344, 256, 0, stream>>>(feat, ftr_t, xyz, inds, new_xyz, idx,
                                       w1, w2, w3, W1b, W2b, W3b, stats);
  conv1_k<<<1024, 256, 0, stream>>>(xyz, ftr_t, idx, new_xyz, W1b, b1, Y1, s1sum, s1sq);
  convB_k<128,false,4><<<1024, 256, 0, stream>>>(Y1, W2b, b2, g1, be1, s1sum, s1sq, Y2, nullptr, s2sum, s2sq);
  convB_k<256,true ,4><<<1024, 256, 0, stream>>>(Y2, W3b, b3, g2, be2, s2sum, s2sq, nullptr, Ymm, s3sum, s3sq);
  finalize_k<<<256, 256, 0, stream>>>(Ymm, g3, be3, s3sum, s3sq, out_feat);
}